// Round 6
// baseline (286.264 us; speedup 1.0000x reference)
//
#include <hip/hip_runtime.h>

#define NSTEP 64
#define HDIM 1024
#define BDIM 2048
#define OHH 511

// ---------------------------------------------------------------------------
// Kernel 1: precompute transposed coefficient tables.
//   etab[s][k][lane]  (float4 c,s,sp,cp), slot = s*512 + k*64 + lane,
//     holding even pair p = 8*lane + k  (pair p covers cols 2p, 2p+1)
//   otab same for odd pair j = 8*lane + k (covers cols 2j+1, 2j+2);
//     j == 511 -> identity (absorbs both chain ends)
//   wtab[q][lane] float4 = (cw0,sw0,cw1,sw1) for cols (16*lane+2q, 16*lane+2q+1)
// ---------------------------------------------------------------------------
__global__ void coeff_kernel(const float* __restrict__ omega,
                             const float* __restrict__ ETh,
                             const float* __restrict__ OTh,
                             const float* __restrict__ EPh,
                             const float* __restrict__ OPh,
                             float4* __restrict__ etab,
                             float4* __restrict__ otab,
                             float2* __restrict__ wtab)
{
    int idx = blockIdx.x * 256 + threadIdx.x;
    if (idx < NSTEP * 512) {
        int p = idx & 511;
        float c, s, cp, sp;
        sincosf(ETh[idx], &s, &c);
        sincosf(EPh[idx], &sp, &cp);
        etab[(idx & ~511) | ((p & 7) << 6) | (p >> 3)] = make_float4(c, s, sp, cp);
    } else if (idx < 2 * NSTEP * 512) {
        int i2 = idx - NSTEP * 512;
        int l = i2 >> 9;
        int j = i2 & 511;
        float4 v;
        if (j < OHH) {
            float c, s, cp, sp;
            sincosf(OTh[l * OHH + j], &s, &c);
            sincosf(OPh[l * OHH + j], &sp, &cp);
            v = make_float4(c, s, sp, cp);
        } else {
            v = make_float4(1.f, 0.f, 1.f, 0.f);  // identity rotation
        }
        otab[(i2 & ~511) | ((j & 7) << 6) | (j >> 3)] = v;
    } else if (idx < 2 * NSTEP * 512 + HDIM) {
        int c = idx - 2 * NSTEP * 512;
        float cw, sw;
        sincosf(omega[c], &sw, &cw);
        int p = c >> 1;
        wtab[(((p & 7) << 6) | (p >> 3)) * 2 + (c & 1)] = make_float2(cw, sw);
    }
}

// One full even+odd step consuming in-register coefficient set (EC, OC, OC0).
// Even boundary pairs (k=0,7) first so the 4 boundary shuffles issue early.
#define DO_STEP(EC, OC, OC0)                                                  \
    {                                                                         \
        _Pragma("unroll")                                                     \
        for (int t = 0; t < 2; ++t) {                                         \
            int k = t ? 7 : 0;                                                \
            float c = EC[k].x, sn = EC[k].y, sp = EC[k].z, cp = EC[k].w;      \
            float ar = xr[2*k],   ai = xi[2*k];                               \
            float br = xr[2*k+1], bi = xi[2*k+1];                             \
            float tr = c*ar - sn*br;                                          \
            float ti = c*ai - sn*bi;                                          \
            xr[2*k]   = sp*tr - cp*ti;                                        \
            xi[2*k]   = sp*ti + cp*tr;                                        \
            xr[2*k+1] = c*br + sn*ar;                                         \
            xi[2*k+1] = c*bi + sn*ai;                                         \
        }                                                                     \
        float xnr = __shfl_down(xr[0], 1, 64);                                \
        float xni = __shfl_down(xi[0], 1, 64);                                \
        float xlr = __shfl_up(xr[15], 1, 64);                                 \
        float xli = __shfl_up(xi[15], 1, 64);                                 \
        _Pragma("unroll")                                                     \
        for (int k = 1; k < 7; ++k) {                                         \
            float c = EC[k].x, sn = EC[k].y, sp = EC[k].z, cp = EC[k].w;      \
            float ar = xr[2*k],   ai = xi[2*k];                               \
            float br = xr[2*k+1], bi = xi[2*k+1];                             \
            float tr = c*ar - sn*br;                                          \
            float ti = c*ai - sn*bi;                                          \
            xr[2*k]   = sp*tr - cp*ti;                                        \
            xi[2*k]   = sp*ti + cp*tr;                                        \
            xr[2*k+1] = c*br + sn*ar;                                         \
            xi[2*k+1] = c*bi + sn*ai;                                         \
        }                                                                     \
        _Pragma("unroll")                                                     \
        for (int k = 1; k < 8; ++k) {                                         \
            float c = OC[k-1].x, sn = OC[k-1].y, sp = OC[k-1].z, cp = OC[k-1].w; \
            float ar = xr[2*k-1], ai = xi[2*k-1];                             \
            float br = xr[2*k],   bi = xi[2*k];                               \
            float tr = c*ar - sn*br;                                          \
            float ti = c*ai - sn*bi;                                          \
            xr[2*k-1] = sp*tr - cp*ti;                                        \
            xi[2*k-1] = sp*ti + cp*tr;                                        \
            xr[2*k]   = c*br + sn*ar;                                         \
            xi[2*k]   = c*bi + sn*ai;                                         \
        }                                                                     \
        {                                                                     \
            float c = OC[7].x, sn = OC[7].y, sp = OC[7].z, cp = OC[7].w;      \
            float ar = xr[15], ai = xi[15];                                   \
            float tr = c*ar - sn*xnr;                                         \
            float ti = c*ai - sn*xni;                                         \
            xr[15] = sp*tr - cp*ti;                                           \
            xi[15] = sp*ti + cp*tr;                                           \
        }                                                                     \
        {                                                                     \
            float c = OC0.x, sn = OC0.y;                                      \
            float br = xr[0], bi = xi[0];                                     \
            xr[0] = c*br + sn*xlr;                                            \
            xi[0] = c*bi + sn*xli;                                            \
        }                                                                     \
    }

// ---------------------------------------------------------------------------
// Kernel 2: one wave = ONE row; lane owns 16 consecutive columns in
// registers. ALL coefficient loads are software-pipelined one full step
// ahead via two register sets (A/B) in a 2x-unrolled loop, so the compute
// path consumes only in-register data (R2/R4/R5 showed wall time pinned at
// ~4.4k cyc/step regardless of occupancy -> per-wave serial vmem latency,
// which this removes from the critical path).
// ---------------------------------------------------------------------------
__global__ __launch_bounds__(256, 2) void eunn_kernel(
    const float* __restrict__ x_re,
    const float* __restrict__ x_im,
    const float4* __restrict__ etab,
    const float4* __restrict__ otab,
    const float4* __restrict__ wtab,
    float* __restrict__ out)
{
    const int lane = threadIdx.x & 63;
    const int wave = threadIdx.x >> 6;
    const int row = blockIdx.x * 4 + wave;
    const int colbase = lane << 4;
    const int lanem1 = (lane + 63) & 63;   // oc0 slot: k=7 row of lane-1 (lane0 -> identity)

    float xr[16], xi[16];

    // --- load state (f32), coalesced float4 ---
    {
        const float4* pr = reinterpret_cast<const float4*>(x_re + row * HDIM + colbase);
        const float4* pi = reinterpret_cast<const float4*>(x_im + row * HDIM + colbase);
        #pragma unroll
        for (int q = 0; q < 4; ++q) {
            float4 vr = pr[q];
            float4 vi = pi[q];
            xr[4*q] = vr.x; xr[4*q+1] = vr.y; xr[4*q+2] = vr.z; xr[4*q+3] = vr.w;
            xi[4*q] = vi.x; xi[4*q+1] = vi.y; xi[4*q+2] = vi.z; xi[4*q+3] = vi.w;
        }
    }

    float4 ecA[8], ocA[8], oc0A;
    float4 ecB[8], ocB[8], oc0B;

    // --- prologue: load set A for step 0 ---
    {
        const float4* pe = etab + lane;
        const float4* po = otab + lane;
        oc0A = otab[(7 << 6) + lanem1];
        #pragma unroll
        for (int k = 0; k < 8; ++k) { ecA[k] = pe[k << 6]; ocA[k] = po[k << 6]; }
    }

    for (int s = 0; s < NSTEP; s += 2) {
        // prefetch set B for step s+1 (consumed a full step away)
        {
            const float4* pe = etab + (s + 1) * 512 + lane;
            const float4* po = otab + (s + 1) * 512 + lane;
            oc0B = po[(7 << 6) + lanem1 - lane];
            #pragma unroll
            for (int k = 0; k < 8; ++k) { ecB[k] = pe[k << 6]; ocB[k] = po[k << 6]; }
        }

        DO_STEP(ecA, ocA, oc0A);

        // prefetch set A for step s+2 (clamped dummy on last iter)
        {
            int s2 = (s + 2 < NSTEP) ? (s + 2) : (NSTEP - 1);
            const float4* pe = etab + s2 * 512 + lane;
            const float4* po = otab + s2 * 512 + lane;
            oc0A = po[(7 << 6) + lanem1 - lane];
            #pragma unroll
            for (int k = 0; k < 8; ++k) { ecA[k] = pe[k << 6]; ocA[k] = po[k << 6]; }
        }

        DO_STEP(ecB, ocB, oc0B);
    }

    // --- omega phase + store (coalesced) ---
    float4 wc[8];
    #pragma unroll
    for (int q = 0; q < 8; ++q) wc[q] = wtab[(q << 6) + lane];  // (cw0,sw0,cw1,sw1) cols 2q,2q+1

    float4* pre = reinterpret_cast<float4*>(out + row * HDIM + colbase);
    float4* pim = reinterpret_cast<float4*>(out + BDIM * HDIM + row * HDIM + colbase);
    #pragma unroll
    for (int h = 0; h < 4; ++h) {
        float4 wa = wc[2*h];
        float4 wb = wc[2*h + 1];
        float4 vr, vi;
        vr.x = xr[4*h]   * wa.x - xi[4*h]   * wa.y;
        vi.x = xr[4*h]   * wa.y + xi[4*h]   * wa.x;
        vr.y = xr[4*h+1] * wa.z - xi[4*h+1] * wa.w;
        vi.y = xr[4*h+1] * wa.w + xi[4*h+1] * wa.z;
        vr.z = xr[4*h+2] * wb.x - xi[4*h+2] * wb.y;
        vi.z = xr[4*h+2] * wb.y + xi[4*h+2] * wb.x;
        vr.w = xr[4*h+3] * wb.z - xi[4*h+3] * wb.w;
        vi.w = xr[4*h+3] * wb.w + xi[4*h+3] * wb.z;
        pre[h] = vr;
        pim[h] = vi;
    }
}

extern "C" void kernel_launch(void* const* d_in, const int* in_sizes, int n_in,
                              void* d_out, int out_size, void* d_ws, size_t ws_size,
                              hipStream_t stream)
{
    const float* x_re  = (const float*)d_in[0];
    const float* x_im  = (const float*)d_in[1];
    const float* omega = (const float*)d_in[2];
    const float* eth   = (const float*)d_in[3];
    const float* oth   = (const float*)d_in[4];
    const float* eph   = (const float*)d_in[5];
    const float* oph   = (const float*)d_in[6];

    char* ws = (char*)d_ws;
    float4* etab = (float4*)ws;                             // 512 KB
    float4* otab = (float4*)(ws + NSTEP * 512 * 16);        // 512 KB
    float2* wtab = (float2*)(ws + 2 * NSTEP * 512 * 16);    // 8 KB

    coeff_kernel<<<260, 256, 0, stream>>>(omega, eth, oth, eph, oph, etab, otab, wtab);
    eunn_kernel<<<BDIM / 4, 256, 0, stream>>>(x_re, x_im, etab, otab,
                                              (const float4*)wtab, (float*)d_out);
}

// Round 7
// 126.654 us; speedup vs baseline: 2.2602x; 2.2602x over previous
//
#include <hip/hip_runtime.h>

#define NSTEP 64
#define HDIM 1024
#define BDIM 2048
#define OHH 511

typedef float v2f __attribute__((ext_vector_type(2)));

__device__ __forceinline__ v2f vsplat(float s) { v2f r; r.x = s; r.y = s; return r; }

// ---------------------------------------------------------------------------
// Kernel 1: precompute transposed coefficient tables (identical to R4 champ).
//   etab[s][k][lane] (float4 c,sn,sp,cp): even pair p = 8*lane+k, cols 2p,2p+1
//   otab same for odd pair j = 8*lane+k (cols 2j+1,2j+2); j==511 -> identity
//   wtab[q][lane] float4 = (cw0,sw0,cw1,sw1) for cols (16*lane+2q, +2q+1)
// ---------------------------------------------------------------------------
__global__ void coeff_kernel(const float* __restrict__ omega,
                             const float* __restrict__ ETh,
                             const float* __restrict__ OTh,
                             const float* __restrict__ EPh,
                             const float* __restrict__ OPh,
                             float4* __restrict__ etab,
                             float4* __restrict__ otab,
                             float2* __restrict__ wtab)
{
    int idx = blockIdx.x * 256 + threadIdx.x;
    if (idx < NSTEP * 512) {
        int p = idx & 511;
        float c, s, cp, sp;
        sincosf(ETh[idx], &s, &c);
        sincosf(EPh[idx], &sp, &cp);
        etab[(idx & ~511) | ((p & 7) << 6) | (p >> 3)] = make_float4(c, s, sp, cp);
    } else if (idx < 2 * NSTEP * 512) {
        int i2 = idx - NSTEP * 512;
        int l = i2 >> 9;
        int j = i2 & 511;
        float4 v;
        if (j < OHH) {
            float c, s, cp, sp;
            sincosf(OTh[l * OHH + j], &s, &c);
            sincosf(OPh[l * OHH + j], &sp, &cp);
            v = make_float4(c, s, sp, cp);
        } else {
            v = make_float4(1.f, 0.f, 1.f, 0.f);  // identity rotation
        }
        otab[(i2 & ~511) | ((j & 7) << 6) | (j >> 3)] = v;
    } else if (idx < 2 * NSTEP * 512 + HDIM) {
        int c = idx - 2 * NSTEP * 512;
        float cw, sw;
        sincosf(omega[c], &sw, &cw);
        int p = c >> 1;
        wtab[(((p & 7) << 6) | (p >> 3)) * 2 + (c & 1)] = make_float2(cw, sw);
    }
}

// Packed complex pair rotation: state A,B are (re,im) v2f; f = (c,sn,sp,cp).
//   t = c*A - sn*B;  B' = c*B + sn*A;  A' = (sp + i*cp) * t
// A'.re = sp*t.re - cp*t.im ; A'.im = sp*t.im + cp*t.re  -> sp*t + (-cp,cp)*t.yx
__device__ __forceinline__ void pair_rot(const float4 f, v2f& A, v2f& B) {
    v2f C = vsplat(f.x), S = vsplat(f.y);
    v2f t = C * A - S * B;
    B = C * B + S * A;
    v2f cps; cps.x = -f.w; cps.y = f.w;
    A = vsplat(f.z) * t + cps * t.yx;
}
// Right-boundary variant: update A only, Bn is neighbor's value.
__device__ __forceinline__ void pair_rot_a(const float4 f, v2f& A, const v2f Bn) {
    v2f t = vsplat(f.x) * A - vsplat(f.y) * Bn;
    v2f cps; cps.x = -f.w; cps.y = f.w;
    A = vsplat(f.z) * t + cps * t.yx;
}

// ---------------------------------------------------------------------------
// Kernel 2: R4 structure (one wave = 2 rows, 1024 waves, transposed tables,
// ec prefetched one step ahead) with PACKED f32 math: state is interleaved
// (re,im) v2f so each pair rotation is ~6 v_pk ops instead of 12 scalar FMAs.
// ---------------------------------------------------------------------------
__global__ __launch_bounds__(256) void eunn_kernel(
    const float* __restrict__ x_re,
    const float* __restrict__ x_im,
    const float4* __restrict__ etab,
    const float4* __restrict__ otab,
    const float4* __restrict__ wtab,
    float* __restrict__ out)
{
    const int lane = threadIdx.x & 63;
    const int wave = threadIdx.x >> 6;
    const int row0 = blockIdx.x * 8 + wave * 2;
    const int colbase = lane << 4;
    const int lanem1 = (lane + 63) & 63;   // oc0 slot: k=7 row of lane-1 (lane0 -> identity)

    v2f x[2][16];   // interleaved (re, im) state

    // --- load state (f32 planes), interleave into v2f regs ---
    #pragma unroll
    for (int r = 0; r < 2; ++r) {
        const float4* pr = reinterpret_cast<const float4*>(x_re + (row0 + r) * HDIM + colbase);
        const float4* pi = reinterpret_cast<const float4*>(x_im + (row0 + r) * HDIM + colbase);
        #pragma unroll
        for (int q = 0; q < 4; ++q) {
            float4 vr = pr[q];
            float4 vi = pi[q];
            x[r][4*q+0].x = vr.x; x[r][4*q+0].y = vi.x;
            x[r][4*q+1].x = vr.y; x[r][4*q+1].y = vi.y;
            x[r][4*q+2].x = vr.z; x[r][4*q+2].y = vi.z;
            x[r][4*q+3].x = vr.w; x[r][4*q+3].y = vi.w;
        }
    }

    // --- preload even coeffs for step 0 (coalesced: lane-stride 16 B) ---
    float4 ec[8];
    {
        const float4* p = etab + lane;
        #pragma unroll
        for (int k = 0; k < 8; ++k) ec[k] = p[k << 6];
    }

    for (int s = 0; s < NSTEP; ++s) {
        // odd coeffs for this step (consumed after even layer)
        const float4* ob = otab + s * 512;
        float4 oc0 = ob[(7 << 6) + lanem1];
        float4 oc[8];
        #pragma unroll
        for (int k = 0; k < 8; ++k) oc[k] = ob[(k << 6) + lane];

        // ---- even layer, boundary pairs first (k=0,7) so shuffles issue early
        pair_rot(ec[0], x[0][0],  x[0][1]);
        pair_rot(ec[0], x[1][0],  x[1][1]);
        pair_rot(ec[7], x[0][14], x[0][15]);
        pair_rot(ec[7], x[1][14], x[1][15]);

        // boundary shuffles on post-even values
        v2f xn[2], xl[2];
        #pragma unroll
        for (int r = 0; r < 2; ++r) {
            xn[r].x = __shfl_down(x[r][0].x, 1, 64);   // right neighbor's col0
            xn[r].y = __shfl_down(x[r][0].y, 1, 64);
            xl[r].x = __shfl_up(x[r][15].x, 1, 64);    // left neighbor's col15
            xl[r].y = __shfl_up(x[r][15].y, 1, 64);
        }

        // remaining even pairs k=1..6
        #pragma unroll
        for (int k = 1; k < 7; ++k) {
            pair_rot(ec[k], x[0][2*k], x[0][2*k+1]);
            pair_rot(ec[k], x[1][2*k], x[1][2*k+1]);
        }

        // prefetch next step's even coeffs (consumed next iteration)
        if (s + 1 < NSTEP) {
            const float4* p = etab + (s + 1) * 512 + lane;
            #pragma unroll
            for (int k = 0; k < 8; ++k) ec[k] = p[k << 6];
        }

        // ---- odd layer: internal pairs oc[k-1] -> local cols (2k-1, 2k)
        #pragma unroll
        for (int k = 1; k < 8; ++k) {
            pair_rot(oc[k-1], x[0][2*k-1], x[0][2*k]);
            pair_rot(oc[k-1], x[1][2*k-1], x[1][2*k]);
        }
        // right boundary (our col15 = "a", neighbor col0 = "b"): update col15
        pair_rot_a(oc[7], x[0][15], xn[0]);
        pair_rot_a(oc[7], x[1][15], xn[1]);
        // left boundary (left col15 = "a", our col0 = "b"): update col0
        {
            v2f C = vsplat(oc0.x), S = vsplat(oc0.y);
            x[0][0] = C * x[0][0] + S * xl[0];
            x[1][0] = C * x[1][0] + S * xl[1];
        }
    }

    // --- omega phase + de-interleave + store (coalesced) ---
    float4 wc[8];
    #pragma unroll
    for (int q = 0; q < 8; ++q) wc[q] = wtab[(q << 6) + lane];  // (cw0,sw0,cw1,sw1) cols 2q,2q+1

    #pragma unroll
    for (int r = 0; r < 2; ++r) {
        float4* pre = reinterpret_cast<float4*>(out + (row0 + r) * HDIM + colbase);
        float4* pim = reinterpret_cast<float4*>(out + BDIM * HDIM + (row0 + r) * HDIM + colbase);
        #pragma unroll
        for (int h = 0; h < 4; ++h) {
            float4 wa = wc[2*h];      // cols 4h, 4h+1
            float4 wb = wc[2*h + 1];  // cols 4h+2, 4h+3
            v2f X0 = x[r][4*h+0], X1 = x[r][4*h+1], X2 = x[r][4*h+2], X3 = x[r][4*h+3];
            float4 vr, vi;
            vr.x = X0.x * wa.x - X0.y * wa.y;  vi.x = X0.x * wa.y + X0.y * wa.x;
            vr.y = X1.x * wa.z - X1.y * wa.w;  vi.y = X1.x * wa.w + X1.y * wa.z;
            vr.z = X2.x * wb.x - X2.y * wb.y;  vi.z = X2.x * wb.y + X2.y * wb.x;
            vr.w = X3.x * wb.z - X3.y * wb.w;  vi.w = X3.x * wb.w + X3.y * wb.z;
            pre[h] = vr;
            pim[h] = vi;
        }
    }
}

extern "C" void kernel_launch(void* const* d_in, const int* in_sizes, int n_in,
                              void* d_out, int out_size, void* d_ws, size_t ws_size,
                              hipStream_t stream)
{
    const float* x_re  = (const float*)d_in[0];
    const float* x_im  = (const float*)d_in[1];
    const float* omega = (const float*)d_in[2];
    const float* eth   = (const float*)d_in[3];
    const float* oth   = (const float*)d_in[4];
    const float* eph   = (const float*)d_in[5];
    const float* oph   = (const float*)d_in[6];

    char* ws = (char*)d_ws;
    float4* etab = (float4*)ws;                             // 512 KB
    float4* otab = (float4*)(ws + NSTEP * 512 * 16);        // 512 KB
    float2* wtab = (float2*)(ws + 2 * NSTEP * 512 * 16);    // 8 KB

    coeff_kernel<<<260, 256, 0, stream>>>(omega, eth, oth, eph, oph, etab, otab, wtab);
    eunn_kernel<<<BDIM / 8, 256, 0, stream>>>(x_re, x_im, etab, otab,
                                              (const float4*)wtab, (float*)d_out);
}